// Round 1
// baseline (398.319 us; speedup 1.0000x reference)
//
#include <hip/hip_runtime.h>
#include <hip/hip_bf16.h>

typedef unsigned short u16;
typedef __attribute__((ext_vector_type(8))) __bf16 bf16x8;
typedef __attribute__((ext_vector_type(4))) float f32x4;

#define LOG2E 1.4426950408889634f

__device__ __forceinline__ u16 f2bf(float f) {
  union { __hip_bfloat16 h; u16 u; } cv;
  cv.h = __float2bfloat16(f);
  return cv.u;
}

__device__ __forceinline__ f32x4 mfma16(bf16x8 a, bf16x8 b, f32x4 c) {
  return __builtin_amdgcn_mfma_f32_16x16x32_bf16(a, b, c, 0, 0, 0);
}

// ---- W[K][N] f32 -> WT[N][K] bf16 (coalesced writes) ----
__global__ void cast_transpose(const float* __restrict__ W, u16* __restrict__ WT,
                               int K, int N) {
  int idx = blockIdx.x * 256 + threadIdx.x;
  if (idx >= K * N) return;
  int n = idx / K, k = idx - n * K;
  WT[idx] = f2bf(W[(size_t)k * N + n]);
}

// ---- LayerNorm over 512, one wave per row, f32 in -> bf16 out ----
__global__ __launch_bounds__(64) void ln_kernel(const float* __restrict__ X,
                                                const float* __restrict__ gam,
                                                const float* __restrict__ bet,
                                                u16* __restrict__ Y) {
  int row = blockIdx.x, l = threadIdx.x;
  const float4* xp = reinterpret_cast<const float4*>(X + (size_t)row * 512);
  float4 a = xp[l], c = xp[l + 64];
  float s  = a.x + a.y + a.z + a.w + c.x + c.y + c.z + c.w;
  float s2 = a.x*a.x + a.y*a.y + a.z*a.z + a.w*a.w
           + c.x*c.x + c.y*c.y + c.z*c.z + c.w*c.w;
#pragma unroll
  for (int m = 1; m < 64; m <<= 1) { s += __shfl_xor(s, m); s2 += __shfl_xor(s2, m); }
  float mu = s * (1.f / 512.f);
  float rs = rsqrtf(s2 * (1.f / 512.f) - mu * mu + 1e-5f);
  const float4* gp = reinterpret_cast<const float4*>(gam);
  const float4* bp = reinterpret_cast<const float4*>(bet);
  float4 g0 = gp[l], g1 = gp[l + 64], b0 = bp[l], b1 = bp[l + 64];
  ushort4 o;
  o.x = f2bf((a.x - mu) * rs * g0.x + b0.x);
  o.y = f2bf((a.y - mu) * rs * g0.y + b0.y);
  o.z = f2bf((a.z - mu) * rs * g0.z + b0.z);
  o.w = f2bf((a.w - mu) * rs * g0.w + b0.w);
  reinterpret_cast<ushort4*>(Y + (size_t)row * 512)[l] = o;
  o.x = f2bf((c.x - mu) * rs * g1.x + b1.x);
  o.y = f2bf((c.y - mu) * rs * g1.y + b1.y);
  o.z = f2bf((c.z - mu) * rs * g1.z + b1.z);
  o.w = f2bf((c.w - mu) * rs * g1.w + b1.w);
  reinterpret_cast<ushort4*>(Y + (size_t)row * 512)[l + 64] = o;
}

// ---- NT GEMM: C[m][n] = sum_k A[m][k] * BT[n][k], bf16 in, fp32 acc ----
// 128x128 tile, BK=32, 256 thr (4 waves, 2x2 of 64x64), LDS stride 40 shorts (pad).
// EPI: 0=qkv scatter  1=proj+residual->f32  2=gelu->bf16  3=out += acc+bias
template <int EPI>
__global__ __launch_bounds__(256) void gemm_bt(
    const u16* __restrict__ A, const u16* __restrict__ BT,
    int M, int N, int K,
    const float* __restrict__ bias,
    const float* __restrict__ resid,
    float* __restrict__ outF,
    u16* __restrict__ outU,
    u16* __restrict__ Qo, u16* __restrict__ Ko, u16* __restrict__ VTo) {
  __shared__ u16 As[128 * 40];
  __shared__ u16 Bs[128 * 40];
  const int tid = threadIdx.x;
  const int wid = tid >> 6, l = tid & 63;
  const int lg = l >> 4, ll = l & 15;
  const int m0 = blockIdx.y * 128, n0 = blockIdx.x * 128;
  const int wm = (wid >> 1) * 64, wn = (wid & 1) * 64;
  const f32x4 zf = {0.f, 0.f, 0.f, 0.f};
  f32x4 acc[4][4];
#pragma unroll
  for (int i = 0; i < 4; i++)
#pragma unroll
    for (int j = 0; j < 4; j++) acc[i][j] = zf;

  const int ra = tid >> 2, c4 = tid & 3;
  for (int kt = 0; kt < K; kt += 32) {
    uint4 a0 = *reinterpret_cast<const uint4*>(A  + (size_t)(m0 + ra)      * K + kt + c4 * 8);
    uint4 a1 = *reinterpret_cast<const uint4*>(A  + (size_t)(m0 + ra + 64) * K + kt + c4 * 8);
    uint4 b0 = *reinterpret_cast<const uint4*>(BT + (size_t)(n0 + ra)      * K + kt + c4 * 8);
    uint4 b1 = *reinterpret_cast<const uint4*>(BT + (size_t)(n0 + ra + 64) * K + kt + c4 * 8);
    __syncthreads();
    *reinterpret_cast<uint4*>(As + ra * 40 + c4 * 8)        = a0;
    *reinterpret_cast<uint4*>(As + (ra + 64) * 40 + c4 * 8) = a1;
    *reinterpret_cast<uint4*>(Bs + ra * 40 + c4 * 8)        = b0;
    *reinterpret_cast<uint4*>(Bs + (ra + 64) * 40 + c4 * 8) = b1;
    __syncthreads();
    bf16x8 af[4], bfr[4];
#pragma unroll
    for (int i = 0; i < 4; i++)
      af[i] = *reinterpret_cast<const bf16x8*>(As + (wm + i * 16 + ll) * 40 + lg * 8);
#pragma unroll
    for (int j = 0; j < 4; j++)
      bfr[j] = *reinterpret_cast<const bf16x8*>(Bs + (wn + j * 16 + ll) * 40 + lg * 8);
#pragma unroll
    for (int i = 0; i < 4; i++)
#pragma unroll
      for (int j = 0; j < 4; j++)
        acc[i][j] = mfma16(af[i], bfr[j], acc[i][j]);
  }

#pragma unroll
  for (int i = 0; i < 4; i++) {
#pragma unroll
    for (int j = 0; j < 4; j++) {
      int col = n0 + wn + j * 16 + ll;
      float bcol = bias[col];
      int rbase = m0 + wm + i * 16 + lg * 4;
#pragma unroll
      for (int r = 0; r < 4; r++) {
        int row = rbase + r;
        float val = acc[i][j][r] + bcol;
        if (EPI == 0) {
          int bi = row >> 11, nseq = row & 2047;
          int t = col >> 9, rem = col & 511;
          int hh = rem >> 6, dd = rem & 63;
          size_t hidx = ((size_t)((bi << 3) + hh) * 2048 + nseq) * 64 + dd;
          if (t == 0)      Qo[hidx] = f2bf(val * 0.125f);   // pre-scale by 1/sqrt(64)
          else if (t == 1) Ko[hidx] = f2bf(val);
          else VTo[((size_t)((bi << 3) + hh) * 64 + dd) * 2048 + nseq] = f2bf(val);
        } else if (EPI == 1) {
          size_t idx = (size_t)row * 512 + col;
          outF[idx] = val + resid[idx];
        } else if (EPI == 2) {
          float gv = 0.5f * val * (1.f + erff(val * 0.70710678f));
          outU[(size_t)row * 2048 + col] = f2bf(gv);
        } else {
          size_t idx = (size_t)row * 512 + col;
          outF[idx] = val + resid[idx];
        }
      }
    }
  }
}

// ---- flash attention: Q[B,H,N,D] (pre-scaled), K[B,H,N,D], VT[B,H,D,N], all bf16
// grid (N/64, H, B), 4 waves; wave owns 16 q rows; KVBLK=64.
__global__ __launch_bounds__(256) void attn_kernel(const u16* __restrict__ Q,
                                                   const u16* __restrict__ Kt,
                                                   const u16* __restrict__ VT,
                                                   u16* __restrict__ O) {
  __shared__ __align__(16) char Pbuf[4][2048];  // per-wave P tile 16x64 bf16, XOR-swizzled
  const int tid = threadIdx.x;
  const int wid = tid >> 6, l = tid & 63;
  const int lg = l >> 4, ll = l & 15;
  const int b = blockIdx.z, h = blockIdx.y;
  const int qbase = blockIdx.x * 64 + wid * 16;
  const size_t hoff = (size_t)(b * 8 + h) * 2048 * 64;
  const u16* Qh = Q + hoff;
  const u16* Kh = Kt + hoff;
  const u16* Vh = VT + hoff;   // [D=64][N=2048]
  char* P = Pbuf[wid];

  bf16x8 qf0 = *reinterpret_cast<const bf16x8*>(Qh + (size_t)(qbase + ll) * 64 + lg * 8);
  bf16x8 qf1 = *reinterpret_cast<const bf16x8*>(Qh + (size_t)(qbase + ll) * 64 + 32 + lg * 8);
  const f32x4 zf = {0.f, 0.f, 0.f, 0.f};
  f32x4 oacc[4] = {zf, zf, zf, zf};
  float mrow[4] = {-INFINITY, -INFINITY, -INFINITY, -INFINITY};
  float lrow[4] = {0.f, 0.f, 0.f, 0.f};

  for (int kb = 0; kb < 2048; kb += 64) {
    // S = Q K^T for 16q x 64k, C-layout: row=lg*4+r, col=s*16+ll
    f32x4 sv[4];
#pragma unroll
    for (int s = 0; s < 4; s++) {
      bf16x8 k0 = *reinterpret_cast<const bf16x8*>(Kh + (size_t)(kb + s * 16 + ll) * 64 + lg * 8);
      bf16x8 k1 = *reinterpret_cast<const bf16x8*>(Kh + (size_t)(kb + s * 16 + ll) * 64 + 32 + lg * 8);
      f32x4 sa = mfma16(qf0, k0, zf);
      sv[s] = mfma16(qf1, k1, sa);
    }
    float tmax[4], rsum[4], alpha[4];
#pragma unroll
    for (int r = 0; r < 4; r++)
      tmax[r] = fmaxf(fmaxf(sv[0][r], sv[1][r]), fmaxf(sv[2][r], sv[3][r]));
#pragma unroll
    for (int m = 1; m < 16; m <<= 1)
#pragma unroll
      for (int r = 0; r < 4; r++)
        tmax[r] = fmaxf(tmax[r], __shfl_xor(tmax[r], m));
#pragma unroll
    for (int r = 0; r < 4; r++) {
      float mnew = fmaxf(mrow[r], tmax[r]);
      alpha[r] = exp2f((mrow[r] - mnew) * LOG2E);
      mrow[r] = mnew;
      rsum[r] = 0.f;
    }
#pragma unroll
    for (int s = 0; s < 4; s++)
#pragma unroll
      for (int r = 0; r < 4; r++) {
        float p = exp2f((sv[s][r] - mrow[r]) * LOG2E);
        sv[s][r] = p;
        rsum[r] += p;
      }
#pragma unroll
    for (int m = 1; m < 16; m <<= 1)
#pragma unroll
      for (int r = 0; r < 4; r++)
        rsum[r] += __shfl_xor(rsum[r], m);
#pragma unroll
    for (int r = 0; r < 4; r++)
      lrow[r] = lrow[r] * alpha[r] + rsum[r];
#pragma unroll
    for (int dt = 0; dt < 4; dt++)
#pragma unroll
      for (int r = 0; r < 4; r++)
        oacc[dt][r] *= alpha[r];

    // P (C-layout) -> LDS, XOR-swizzled so A-frag re-read is ~conflict-free
#pragma unroll
    for (int s = 0; s < 4; s++)
#pragma unroll
      for (int r = 0; r < 4; r++) {
        int prow = lg * 4 + r, pcol = s * 16 + ll;
        int boff = prow * 128 + ((((pcol >> 3) ^ (prow & 7)) << 4) | ((pcol & 7) << 1));
        *reinterpret_cast<u16*>(P + boff) = f2bf(sv[s][r]);
      }
    // PV: A = P[16x32 chunk] from LDS, B = VT rows (contiguous), acc into oacc
#pragma unroll
    for (int pc = 0; pc < 2; pc++) {
      int col16 = pc * 4 + lg;
      bf16x8 pf = *reinterpret_cast<const bf16x8*>(P + ll * 128 + ((col16 ^ (ll & 7)) << 4));
#pragma unroll
      for (int dt = 0; dt < 4; dt++) {
        bf16x8 vf = *reinterpret_cast<const bf16x8*>(
            Vh + (size_t)(dt * 16 + ll) * 2048 + kb + pc * 32 + lg * 8);
        oacc[dt] = mfma16(pf, vf, oacc[dt]);
      }
    }
  }

#pragma unroll
  for (int dt = 0; dt < 4; dt++)
#pragma unroll
    for (int r = 0; r < 4; r++) {
      int row = qbase + lg * 4 + r;
      int col = h * 64 + dt * 16 + ll;
      O[((size_t)(b * 2048) + row) * 512 + col] = f2bf(oacc[dt][r] / lrow[r]);
    }
}

extern "C" void kernel_launch(void* const* d_in, const int* in_sizes, int n_in,
                              void* d_out, int out_size, void* d_ws, size_t ws_size,
                              hipStream_t stream) {
  const float* x      = (const float*)d_in[0];
  const float* ln1_g  = (const float*)d_in[1];
  const float* ln1_b  = (const float*)d_in[2];
  const float* w_qkv  = (const float*)d_in[3];
  const float* b_qkv  = (const float*)d_in[4];
  const float* w_proj = (const float*)d_in[5];
  const float* b_proj = (const float*)d_in[6];
  const float* ln2_g  = (const float*)d_in[7];
  const float* ln2_b  = (const float*)d_in[8];
  const float* w1     = (const float*)d_in[9];
  const float* b1     = (const float*)d_in[10];
  const float* w2     = (const float*)d_in[11];
  const float* b2     = (const float*)d_in[12];
  float* out = (float*)d_out;

  const int M = 8192;  // B*N rows
  char* w = (char*)d_ws;
  u16* wqkvT  = (u16*)w; w += (size_t)1536 * 512 * 2;
  u16* wprojT = (u16*)w; w += (size_t)512 * 512 * 2;
  u16* w1T    = (u16*)w; w += (size_t)2048 * 512 * 2;
  u16* w2T    = (u16*)w; w += (size_t)512 * 2048 * 2;
  u16* h1     = (u16*)w; w += (size_t)M * 512 * 2;
  u16* Qb     = (u16*)w; w += (size_t)M * 512 * 2;
  u16* Kb     = (u16*)w; w += (size_t)M * 512 * 2;
  u16* VTb    = (u16*)w; w += (size_t)M * 512 * 2;
  u16* attn   = (u16*)w; w += (size_t)M * 512 * 2;
  u16* h2     = (u16*)w; w += (size_t)M * 512 * 2;
  u16* mid    = (u16*)w; w += (size_t)M * 2048 * 2;

  cast_transpose<<<(512 * 1536 + 255) / 256, 256, 0, stream>>>(w_qkv, wqkvT, 512, 1536);
  cast_transpose<<<(512 * 512 + 255) / 256, 256, 0, stream>>>(w_proj, wprojT, 512, 512);
  cast_transpose<<<(512 * 2048 + 255) / 256, 256, 0, stream>>>(w1, w1T, 512, 2048);
  cast_transpose<<<(2048 * 512 + 255) / 256, 256, 0, stream>>>(w2, w2T, 2048, 512);

  ln_kernel<<<M, 64, 0, stream>>>(x, ln1_g, ln1_b, h1);

  gemm_bt<0><<<dim3(1536 / 128, M / 128), 256, 0, stream>>>(
      h1, wqkvT, M, 1536, 512, b_qkv, nullptr, nullptr, nullptr, Qb, Kb, VTb);

  attn_kernel<<<dim3(2048 / 64, 8, 4), 256, 0, stream>>>(Qb, Kb, VTb, attn);

  gemm_bt<1><<<dim3(512 / 128, M / 128), 256, 0, stream>>>(
      attn, wprojT, M, 512, 512, b_proj, x, out, nullptr, nullptr, nullptr, nullptr);

  ln_kernel<<<M, 64, 0, stream>>>(out, ln2_g, ln2_b, h2);

  gemm_bt<2><<<dim3(2048 / 128, M / 128), 256, 0, stream>>>(
      h2, w1T, M, 2048, 512, b1, nullptr, nullptr, mid, nullptr, nullptr, nullptr);

  gemm_bt<3><<<dim3(512 / 128, M / 128), 256, 0, stream>>>(
      mid, w2T, M, 512, 2048, b2, out, out, nullptr, nullptr, nullptr, nullptr);
}

// Round 2
// 323.063 us; speedup vs baseline: 1.2329x; 1.2329x over previous
//
#include <hip/hip_runtime.h>
#include <hip/hip_bf16.h>

typedef unsigned short u16;
typedef unsigned int u32;
typedef __attribute__((ext_vector_type(8))) __bf16 bf16x8;
typedef __attribute__((ext_vector_type(4))) float f32x4;
typedef __attribute__((ext_vector_type(16))) float f32x16;

#define LOG2E 1.4426950408889634f

__device__ __forceinline__ u16 f2bf(float f) {
  union { __hip_bfloat16 h; u16 u; } cv;
  cv.h = __float2bfloat16(f);
  return cv.u;
}

__device__ __forceinline__ u32 pk2(float a, float b) {
  return (u32)f2bf(a) | ((u32)f2bf(b) << 16);
}

__device__ __forceinline__ f32x4 mfma16(bf16x8 a, bf16x8 b, f32x4 c) {
  return __builtin_amdgcn_mfma_f32_16x16x32_bf16(a, b, c, 0, 0, 0);
}
__device__ __forceinline__ f32x16 mfma32(bf16x8 a, bf16x8 b, f32x16 c) {
  return __builtin_amdgcn_mfma_f32_32x32x16_bf16(a, b, c, 0, 0, 0);
}

// ---- W[K][N] f32 -> WT[N][K] bf16 (coalesced writes) ----
__global__ void cast_transpose(const float* __restrict__ W, u16* __restrict__ WT,
                               int K, int N) {
  int idx = blockIdx.x * 256 + threadIdx.x;
  if (idx >= K * N) return;
  int n = idx / K, k = idx - n * K;
  WT[idx] = f2bf(W[(size_t)k * N + n]);
}

// ---- LayerNorm over 512, one wave per row, f32 in -> bf16 out ----
__global__ __launch_bounds__(64) void ln_kernel(const float* __restrict__ X,
                                                const float* __restrict__ gam,
                                                const float* __restrict__ bet,
                                                u16* __restrict__ Y) {
  int row = blockIdx.x, l = threadIdx.x;
  const float4* xp = reinterpret_cast<const float4*>(X + (size_t)row * 512);
  float4 a = xp[l], c = xp[l + 64];
  float s  = a.x + a.y + a.z + a.w + c.x + c.y + c.z + c.w;
  float s2 = a.x*a.x + a.y*a.y + a.z*a.z + a.w*a.w
           + c.x*c.x + c.y*c.y + c.z*c.z + c.w*c.w;
#pragma unroll
  for (int m = 1; m < 64; m <<= 1) { s += __shfl_xor(s, m); s2 += __shfl_xor(s2, m); }
  float mu = s * (1.f / 512.f);
  float rs = rsqrtf(s2 * (1.f / 512.f) - mu * mu + 1e-5f);
  const float4* gp = reinterpret_cast<const float4*>(gam);
  const float4* bp = reinterpret_cast<const float4*>(bet);
  float4 g0 = gp[l], g1 = gp[l + 64], b0 = bp[l], b1 = bp[l + 64];
  ushort4 o;
  o.x = f2bf((a.x - mu) * rs * g0.x + b0.x);
  o.y = f2bf((a.y - mu) * rs * g0.y + b0.y);
  o.z = f2bf((a.z - mu) * rs * g0.z + b0.z);
  o.w = f2bf((a.w - mu) * rs * g0.w + b0.w);
  reinterpret_cast<ushort4*>(Y + (size_t)row * 512)[l] = o;
  o.x = f2bf((c.x - mu) * rs * g1.x + b1.x);
  o.y = f2bf((c.y - mu) * rs * g1.y + b1.y);
  o.z = f2bf((c.z - mu) * rs * g1.z + b1.z);
  o.w = f2bf((c.w - mu) * rs * g1.w + b1.w);
  reinterpret_cast<ushort4*>(Y + (size_t)row * 512)[l + 64] = o;
}

// ---- NT GEMM: C[m][n] = sum_k A[m][k] * BT[n][k], bf16 in, fp32 acc ----
// 128x128 tile, BK=32, 256 thr (4 waves, 2x2 of 64x64), LDS stride 40 shorts (pad).
// EPI: 0=qkv scatter  1=proj+residual->f32  2=gelu->bf16  3=out += acc+bias
template <int EPI>
__global__ __launch_bounds__(256) void gemm_bt(
    const u16* __restrict__ A, const u16* __restrict__ BT,
    int M, int N, int K,
    const float* __restrict__ bias,
    const float* __restrict__ resid,
    float* __restrict__ outF,
    u16* __restrict__ outU,
    u16* __restrict__ Qo, u16* __restrict__ Ko, u16* __restrict__ VTo) {
  __shared__ u16 As[128 * 40];
  __shared__ u16 Bs[128 * 40];
  const int tid = threadIdx.x;
  const int wid = tid >> 6, l = tid & 63;
  const int lg = l >> 4, ll = l & 15;
  const int m0 = blockIdx.y * 128, n0 = blockIdx.x * 128;
  const int wm = (wid >> 1) * 64, wn = (wid & 1) * 64;
  const f32x4 zf = {0.f, 0.f, 0.f, 0.f};
  f32x4 acc[4][4];
#pragma unroll
  for (int i = 0; i < 4; i++)
#pragma unroll
    for (int j = 0; j < 4; j++) acc[i][j] = zf;

  const int ra = tid >> 2, c4 = tid & 3;
  for (int kt = 0; kt < K; kt += 32) {
    uint4 a0 = *reinterpret_cast<const uint4*>(A  + (size_t)(m0 + ra)      * K + kt + c4 * 8);
    uint4 a1 = *reinterpret_cast<const uint4*>(A  + (size_t)(m0 + ra + 64) * K + kt + c4 * 8);
    uint4 b0 = *reinterpret_cast<const uint4*>(BT + (size_t)(n0 + ra)      * K + kt + c4 * 8);
    uint4 b1 = *reinterpret_cast<const uint4*>(BT + (size_t)(n0 + ra + 64) * K + kt + c4 * 8);
    __syncthreads();
    *reinterpret_cast<uint4*>(As + ra * 40 + c4 * 8)        = a0;
    *reinterpret_cast<uint4*>(As + (ra + 64) * 40 + c4 * 8) = a1;
    *reinterpret_cast<uint4*>(Bs + ra * 40 + c4 * 8)        = b0;
    *reinterpret_cast<uint4*>(Bs + (ra + 64) * 40 + c4 * 8) = b1;
    __syncthreads();
    bf16x8 af[4], bfr[4];
#pragma unroll
    for (int i = 0; i < 4; i++)
      af[i] = *reinterpret_cast<const bf16x8*>(As + (wm + i * 16 + ll) * 40 + lg * 8);
#pragma unroll
    for (int j = 0; j < 4; j++)
      bfr[j] = *reinterpret_cast<const bf16x8*>(Bs + (wn + j * 16 + ll) * 40 + lg * 8);
#pragma unroll
    for (int i = 0; i < 4; i++)
#pragma unroll
      for (int j = 0; j < 4; j++)
        acc[i][j] = mfma16(af[i], bfr[j], acc[i][j]);
  }

#pragma unroll
  for (int i = 0; i < 4; i++) {
#pragma unroll
    for (int j = 0; j < 4; j++) {
      int col = n0 + wn + j * 16 + ll;
      float bcol = bias[col];
      int rbase = m0 + wm + i * 16 + lg * 4;
#pragma unroll
      for (int r = 0; r < 4; r++) {
        int row = rbase + r;
        float val = acc[i][j][r] + bcol;
        if (EPI == 0) {
          int bi = row >> 11, nseq = row & 2047;
          int t = col >> 9, rem = col & 511;
          int hh = rem >> 6, dd = rem & 63;
          size_t hidx = ((size_t)((bi << 3) + hh) * 2048 + nseq) * 64 + dd;
          // Q pre-scaled by 1/sqrt(64) * log2(e) so attn uses exp2 directly
          if (t == 0)      Qo[hidx] = f2bf(val * (0.125f * LOG2E));
          else if (t == 1) Ko[hidx] = f2bf(val);
          else VTo[((size_t)((bi << 3) + hh) * 64 + dd) * 2048 + nseq] = f2bf(val);
        } else if (EPI == 1) {
          size_t idx = (size_t)row * 512 + col;
          outF[idx] = val + resid[idx];
        } else if (EPI == 2) {
          float gv = 0.5f * val * (1.f + erff(val * 0.70710678f));
          outU[(size_t)row * 2048 + col] = f2bf(gv);
        } else {
          size_t idx = (size_t)row * 512 + col;
          outF[idx] = val + resid[idx];
        }
      }
    }
  }
}

// ---- flash attention, swapped-QK^T in-register softmax ----
// Q[B,H,N,D] (pre-scaled by 0.125*log2e), K[B,H,N,D], VT[B,H,D,N], all bf16.
// grid (N/128, H, B), 4 waves; wave owns 32 q rows; KVBLK=64; no LDS, no barriers.
// S^T = mfma32(K_frag, Q_frag): lane holds col q = l&31, rows k = (r&3)+8*(r>>2)+4*(l>>5).
__global__ __launch_bounds__(256) void attn_kernel(const u16* __restrict__ Q,
                                                   const u16* __restrict__ Kt,
                                                   const u16* __restrict__ VT,
                                                   u16* __restrict__ O) {
  const int tid = threadIdx.x;
  const int wid = tid >> 6, l = tid & 63;
  const int lq = l & 31, h = l >> 5;
  const int b = blockIdx.z, hd = blockIdx.y;
  const int qbase = blockIdx.x * 128 + wid * 32;
  const size_t hoff = (size_t)(b * 8 + hd) * 2048 * 64;
  const u16* Qh = Q + hoff;
  const u16* Kh = Kt + hoff;
  const u16* Vh = VT + hoff;   // [D=64][N=2048]

  // Q fragments (B-operand): lane holds Q[q=lq][d = s*16 + h*8 .. +8]
  bf16x8 qf[4];
#pragma unroll
  for (int s = 0; s < 4; s++)
    qf[s] = *reinterpret_cast<const bf16x8*>(Qh + (size_t)(qbase + lq) * 64 + s * 16 + h * 8);

  f32x16 oacc[2];
#pragma unroll
  for (int r = 0; r < 16; r++) { oacc[0][r] = 0.f; oacc[1][r] = 0.f; }
  float m = -INFINITY, lsum = 0.f;

  for (int kb = 0; kb < 2048; kb += 64) {
    // S^T: two 32x32 tiles (k-halves), A = K rows, B = Q rows
    f32x16 st[2];
#pragma unroll
    for (int t = 0; t < 2; t++) {
      f32x16 a;
#pragma unroll
      for (int r = 0; r < 16; r++) a[r] = 0.f;
#pragma unroll
      for (int s = 0; s < 4; s++) {
        bf16x8 kf = *reinterpret_cast<const bf16x8*>(
            Kh + (size_t)(kb + t * 32 + lq) * 64 + s * 16 + h * 8);
        a = mfma32(kf, qf[s], a);
      }
      st[t] = a;
    }

    // tile max for q=lq (in-lane over 32, then combine halves)
    float pmax = st[0][0];
#pragma unroll
    for (int j = 1; j < 16; j++) pmax = fmaxf(pmax, st[0][j]);
#pragma unroll
    for (int j = 0; j < 16; j++) pmax = fmaxf(pmax, st[1][j]);
    pmax = fmaxf(pmax, __shfl_xor(pmax, 32));

    // defer-max: rescale only when the running max grew by > 8 (log2 domain)
    if (!__all(pmax - m <= 8.0f)) {
      float mnew = fmaxf(m, pmax);
      float alpha = exp2f(m - mnew);
      m = mnew;
      lsum *= alpha;
#pragma unroll
      for (int r = 0; r < 16; r++) {
        float ar = __shfl(alpha, (r & 3) + 8 * (r >> 2) + 4 * h);
        oacc[0][r] *= ar;
        oacc[1][r] *= ar;
      }
    }

    // P = exp2(S - m), row-sum
    float rs = 0.f;
#pragma unroll
    for (int t = 0; t < 2; t++)
#pragma unroll
      for (int j = 0; j < 16; j++) {
        float p = exp2f(st[t][j] - m);
        st[t][j] = p;
        rs += p;
      }
    rs += __shfl_xor(rs, 32);
    lsum += rs;

    // Build PV A-fragments in-register: for k-slice ks, lane needs
    // P[q=lq][k = ks*16 + h*8 + 0..7]; half of those live at lane^32.
    uint4 pa[4];
#pragma unroll
    for (int ks = 0; ks < 4; ks++) {
      const int t = ks >> 1, rlo = (ks & 1) * 8;
      u32 w0 = pk2(st[t][rlo + 0], st[t][rlo + 1]);
      u32 w1 = pk2(st[t][rlo + 2], st[t][rlo + 3]);
      u32 w2 = pk2(st[t][rlo + 4], st[t][rlo + 5]);
      u32 w3 = pk2(st[t][rlo + 6], st[t][rlo + 7]);
      u32 ka = h ? w2 : w0, kb2 = h ? w3 : w1;   // keep (rows this half owns for its j-range)
      u32 sa = h ? w0 : w2, sb = h ? w1 : w3;    // send (rows the partner half needs)
      u32 ra = (u32)__shfl_xor((int)sa, 32);
      u32 rb = (u32)__shfl_xor((int)sb, 32);
      pa[ks].x = h ? ra : ka;
      pa[ks].y = h ? rb : kb2;
      pa[ks].z = h ? ka : ra;
      pa[ks].w = h ? kb2 : rb;
    }

    // PV: O[q][d] += P * V, B-frag from VT rows (contiguous)
#pragma unroll
    for (int dt = 0; dt < 2; dt++)
#pragma unroll
      for (int ks = 0; ks < 4; ks++) {
        bf16x8 vf = *reinterpret_cast<const bf16x8*>(
            Vh + (size_t)(dt * 32 + lq) * 2048 + kb + ks * 16 + h * 8);
        union { uint4 u; bf16x8 v; } pu;
        pu.u = pa[ks];
        oacc[dt] = mfma32(pu.v, vf, oacc[dt]);
      }
  }

  // epilogue: divide by l (broadcast from stat lane), write [B,N,H*D]
  float linv = 1.0f / lsum;
#pragma unroll
  for (int r = 0; r < 16; r++) {
    const int qr = (r & 3) + 8 * (r >> 2) + 4 * h;
    float lb = __shfl(linv, qr);
    int row = qbase + qr;
#pragma unroll
    for (int dt = 0; dt < 2; dt++) {
      int col = hd * 64 + dt * 32 + lq;
      O[((size_t)(b * 2048) + row) * 512 + col] = f2bf(oacc[dt][r] * lb);
    }
  }
}

extern "C" void kernel_launch(void* const* d_in, const int* in_sizes, int n_in,
                              void* d_out, int out_size, void* d_ws, size_t ws_size,
                              hipStream_t stream) {
  const float* x      = (const float*)d_in[0];
  const float* ln1_g  = (const float*)d_in[1];
  const float* ln1_b  = (const float*)d_in[2];
  const float* w_qkv  = (const float*)d_in[3];
  const float* b_qkv  = (const float*)d_in[4];
  const float* w_proj = (const float*)d_in[5];
  const float* b_proj = (const float*)d_in[6];
  const float* ln2_g  = (const float*)d_in[7];
  const float* ln2_b  = (const float*)d_in[8];
  const float* w1     = (const float*)d_in[9];
  const float* b1     = (const float*)d_in[10];
  const float* w2     = (const float*)d_in[11];
  const float* b2     = (const float*)d_in[12];
  float* out = (float*)d_out;

  const int M = 8192;  // B*N rows
  char* w = (char*)d_ws;
  u16* wqkvT  = (u16*)w; w += (size_t)1536 * 512 * 2;
  u16* wprojT = (u16*)w; w += (size_t)512 * 512 * 2;
  u16* w1T    = (u16*)w; w += (size_t)2048 * 512 * 2;
  u16* w2T    = (u16*)w; w += (size_t)512 * 2048 * 2;
  u16* h1     = (u16*)w; w += (size_t)M * 512 * 2;
  u16* Qb     = (u16*)w; w += (size_t)M * 512 * 2;
  u16* Kb     = (u16*)w; w += (size_t)M * 512 * 2;
  u16* VTb    = (u16*)w; w += (size_t)M * 512 * 2;
  u16* attn   = (u16*)w; w += (size_t)M * 512 * 2;
  u16* h2     = (u16*)w; w += (size_t)M * 512 * 2;
  u16* mid    = (u16*)w; w += (size_t)M * 2048 * 2;

  cast_transpose<<<(512 * 1536 + 255) / 256, 256, 0, stream>>>(w_qkv, wqkvT, 512, 1536);
  cast_transpose<<<(512 * 512 + 255) / 256, 256, 0, stream>>>(w_proj, wprojT, 512, 512);
  cast_transpose<<<(512 * 2048 + 255) / 256, 256, 0, stream>>>(w1, w1T, 512, 2048);
  cast_transpose<<<(2048 * 512 + 255) / 256, 256, 0, stream>>>(w2, w2T, 2048, 512);

  ln_kernel<<<M, 64, 0, stream>>>(x, ln1_g, ln1_b, h1);

  gemm_bt<0><<<dim3(1536 / 128, M / 128), 256, 0, stream>>>(
      h1, wqkvT, M, 1536, 512, b_qkv, nullptr, nullptr, nullptr, Qb, Kb, VTb);

  attn_kernel<<<dim3(2048 / 128, 8, 4), 256, 0, stream>>>(Qb, Kb, VTb, attn);

  gemm_bt<1><<<dim3(512 / 128, M / 128), 256, 0, stream>>>(
      attn, wprojT, M, 512, 512, b_proj, x, out, nullptr, nullptr, nullptr, nullptr);

  ln_kernel<<<M, 64, 0, stream>>>(out, ln2_g, ln2_b, h2);

  gemm_bt<2><<<dim3(2048 / 128, M / 128), 256, 0, stream>>>(
      h2, w1T, M, 2048, 512, b1, nullptr, nullptr, mid, nullptr, nullptr, nullptr);

  gemm_bt<3><<<dim3(512 / 128, M / 128), 256, 0, stream>>>(
      mid, w2T, M, 512, 2048, b2, out, out, nullptr, nullptr, nullptr, nullptr);
}

// Round 3
// 281.131 us; speedup vs baseline: 1.4168x; 1.1492x over previous
//
#include <hip/hip_runtime.h>
#include <hip/hip_bf16.h>

typedef unsigned short u16;
typedef unsigned int u32;
typedef __attribute__((ext_vector_type(8))) __bf16 bf16x8;
typedef __attribute__((ext_vector_type(4))) float f32x4;
typedef __attribute__((ext_vector_type(16))) float f32x16;

#define LOG2E 1.4426950408889634f

__device__ __forceinline__ u16 f2bf(float f) {
  union { __hip_bfloat16 h; u16 u; } cv;
  cv.h = __float2bfloat16(f);
  return cv.u;
}

__device__ __forceinline__ u32 pk2(float a, float b) {
  return (u32)f2bf(a) | ((u32)f2bf(b) << 16);
}

__device__ __forceinline__ f32x4 mfma16(bf16x8 a, bf16x8 b, f32x4 c) {
  return __builtin_amdgcn_mfma_f32_16x16x32_bf16(a, b, c, 0, 0, 0);
}
__device__ __forceinline__ f32x16 mfma32(bf16x8 a, bf16x8 b, f32x16 c) {
  return __builtin_amdgcn_mfma_f32_32x32x16_bf16(a, b, c, 0, 0, 0);
}

// async global->LDS, 16B per lane, dest = wave-uniform base + lane*16
__device__ __forceinline__ void gload16(const u16* g, u16* lds) {
  __builtin_amdgcn_global_load_lds(
      (const __attribute__((address_space(1))) u32*)g,
      (__attribute__((address_space(3))) u32*)lds, 16, 0, 0);
}

// ---- W[K][N] f32 -> WT[N][K] bf16 (coalesced writes) ----
__global__ void cast_transpose(const float* __restrict__ W, u16* __restrict__ WT,
                               int K, int N) {
  int idx = blockIdx.x * 256 + threadIdx.x;
  if (idx >= K * N) return;
  int n = idx / K, k = idx - n * K;
  WT[idx] = f2bf(W[(size_t)k * N + n]);
}

// ---- LayerNorm over 512, one wave per row, f32 in -> bf16 out ----
__global__ __launch_bounds__(64) void ln_kernel(const float* __restrict__ X,
                                                const float* __restrict__ gam,
                                                const float* __restrict__ bet,
                                                u16* __restrict__ Y) {
  int row = blockIdx.x, l = threadIdx.x;
  const float4* xp = reinterpret_cast<const float4*>(X + (size_t)row * 512);
  float4 a = xp[l], c = xp[l + 64];
  float s  = a.x + a.y + a.z + a.w + c.x + c.y + c.z + c.w;
  float s2 = a.x*a.x + a.y*a.y + a.z*a.z + a.w*a.w
           + c.x*c.x + c.y*c.y + c.z*c.z + c.w*c.w;
#pragma unroll
  for (int m = 1; m < 64; m <<= 1) { s += __shfl_xor(s, m); s2 += __shfl_xor(s2, m); }
  float mu = s * (1.f / 512.f);
  float rs = rsqrtf(s2 * (1.f / 512.f) - mu * mu + 1e-5f);
  const float4* gp = reinterpret_cast<const float4*>(gam);
  const float4* bp = reinterpret_cast<const float4*>(bet);
  float4 g0 = gp[l], g1 = gp[l + 64], b0 = bp[l], b1 = bp[l + 64];
  ushort4 o;
  o.x = f2bf((a.x - mu) * rs * g0.x + b0.x);
  o.y = f2bf((a.y - mu) * rs * g0.y + b0.y);
  o.z = f2bf((a.z - mu) * rs * g0.z + b0.z);
  o.w = f2bf((a.w - mu) * rs * g0.w + b0.w);
  reinterpret_cast<ushort4*>(Y + (size_t)row * 512)[l] = o;
  o.x = f2bf((c.x - mu) * rs * g1.x + b1.x);
  o.y = f2bf((c.y - mu) * rs * g1.y + b1.y);
  o.z = f2bf((c.z - mu) * rs * g1.z + b1.z);
  o.w = f2bf((c.w - mu) * rs * g1.w + b1.w);
  reinterpret_cast<ushort4*>(Y + (size_t)row * 512)[l + 64] = o;
}

// ---- NT GEMM: C[m][n] = sum_k A[m][k] * BT[n][k], bf16 in, fp32 acc ----
// BMxBN=BMx128 tile, BK=32, 256 thr (4 waves, 2x2), global_load_lds staging,
// linear LDS (stride 32 shorts), m97 2-barrier structure.
// EPI: 0=qkv scatter  1=proj+residual->f32  2=gelu->bf16  3=out += acc+bias
template <int EPI, int BM>
__global__ __launch_bounds__(256) void gemm_bt(
    const u16* __restrict__ A, const u16* __restrict__ BT,
    int M, int N, int K,
    const float* __restrict__ bias,
    const float* __restrict__ resid,
    float* __restrict__ outF,
    u16* __restrict__ outU,
    u16* __restrict__ Qo, u16* __restrict__ Ko, u16* __restrict__ VTo) {
  constexpr int MFR = BM / 32;       // M fragments per wave (16-rows each)
  constexpr int CA = BM / 64;        // A chunks (1KB) staged per wave
  __shared__ u16 As[BM * 32];
  __shared__ u16 Bs[128 * 32];
  const int tid = threadIdx.x;
  const int wid = tid >> 6, l = tid & 63;
  const int lg = l >> 4, ll = l & 15;
  const int m0 = blockIdx.y * BM, n0 = blockIdx.x * 128;
  const int wm = (wid >> 1) * (BM / 2), wn = (wid & 1) * 64;
  const f32x4 zf = {0.f, 0.f, 0.f, 0.f};
  f32x4 acc[MFR][4];
#pragma unroll
  for (int i = 0; i < MFR; i++)
#pragma unroll
    for (int j = 0; j < 4; j++) acc[i][j] = zf;

  const int srow = l >> 2, scol = (l & 3) * 8;
  const u16* Ag = A + (size_t)(m0 + wid * CA * 16 + srow) * K + scol;
  const u16* Bg = BT + (size_t)(n0 + wid * 32 + srow) * K + scol;
  u16* lA = As + wid * CA * 512;
  u16* lB = Bs + wid * 1024;

  for (int kt = 0; kt < K; kt += 32) {
    __syncthreads();
#pragma unroll
    for (int c = 0; c < CA; c++)
      gload16(Ag + (size_t)c * 16 * K + kt, lA + c * 512);
    gload16(Bg + kt, lB);
    gload16(Bg + (size_t)16 * K + kt, lB + 512);
    __syncthreads();
    bf16x8 af[MFR], bfr[4];
#pragma unroll
    for (int i = 0; i < MFR; i++)
      af[i] = *reinterpret_cast<const bf16x8*>(As + (wm + i * 16 + ll) * 32 + lg * 8);
#pragma unroll
    for (int j = 0; j < 4; j++)
      bfr[j] = *reinterpret_cast<const bf16x8*>(Bs + (wn + j * 16 + ll) * 32 + lg * 8);
#pragma unroll
    for (int i = 0; i < MFR; i++)
#pragma unroll
      for (int j = 0; j < 4; j++)
        acc[i][j] = mfma16(af[i], bfr[j], acc[i][j]);
  }

#pragma unroll
  for (int i = 0; i < MFR; i++) {
#pragma unroll
    for (int j = 0; j < 4; j++) {
      int col = n0 + wn + j * 16 + ll;
      float bcol = bias[col];
      int rbase = m0 + wm + i * 16 + lg * 4;
#pragma unroll
      for (int r = 0; r < 4; r++) {
        int row = rbase + r;
        float val = acc[i][j][r] + bcol;
        if (EPI == 0) {
          int bi = row >> 11, nseq = row & 2047;
          int t = col >> 9, rem = col & 511;
          int hh = rem >> 6, dd = rem & 63;
          size_t hidx = ((size_t)((bi << 3) + hh) * 2048 + nseq) * 64 + dd;
          // Q pre-scaled by 1/sqrt(64) * log2(e) so attn uses exp2 directly
          if (t == 0)      Qo[hidx] = f2bf(val * (0.125f * LOG2E));
          else if (t == 1) Ko[hidx] = f2bf(val);
          else VTo[((size_t)((bi << 3) + hh) * 64 + dd) * 2048 + nseq] = f2bf(val);
        } else if (EPI == 1) {
          size_t idx = (size_t)row * 512 + col;
          outF[idx] = val + resid[idx];
        } else if (EPI == 2) {
          float gv = 0.5f * val * (1.f + erff(val * 0.70710678f));
          outU[(size_t)row * 2048 + col] = f2bf(gv);
        } else {
          size_t idx = (size_t)row * 512 + col;
          outF[idx] = val + resid[idx];
        }
      }
    }
  }
}

// ---- flash attention, swapped-QK^T in-register softmax, pipelined loads ----
// Q[B,H,N,D] (pre-scaled by 0.125*log2e), K[B,H,N,D], VT[B,H,D,N], all bf16.
// grid (N/128, H, B), 4 waves; wave owns 32 q rows; KVBLK=64; no LDS/barriers.
// S^T = mfma32(K_frag, Q_frag): lane holds col q = l&31, rows k=(r&3)+8*(r>>2)+4*(l>>5).
__device__ __forceinline__ void attn_tile(
    int KB, int KNB, const u16* __restrict__ Kh, const u16* __restrict__ Vh,
    const bf16x8 (&qf)[4], bf16x8 (&KC)[2][4], bf16x8 (&KN)[2][4],
    f32x16 (&oacc)[2], float& m, float& lsum, int lq, int h) {
  // V(t) loads issued first: softmax phase hides their latency
  bf16x8 vreg[2][4];
#pragma unroll
  for (int dt = 0; dt < 2; dt++)
#pragma unroll
    for (int ks = 0; ks < 4; ks++)
      vreg[dt][ks] = *reinterpret_cast<const bf16x8*>(
          Vh + (size_t)(dt * 32 + lq) * 2048 + KB + ks * 16 + h * 8);

  // QK^T from current K regs
  f32x16 st[2];
#pragma unroll
  for (int t = 0; t < 2; t++) {
    f32x16 a;
#pragma unroll
    for (int r = 0; r < 16; r++) a[r] = 0.f;
#pragma unroll
    for (int s = 0; s < 4; s++) a = mfma32(KC[t][s], qf[s], a);
    st[t] = a;
  }

  // prefetch next tile's K (crosses into next tile; wraps harmlessly at end)
#pragma unroll
  for (int t = 0; t < 2; t++)
#pragma unroll
    for (int s = 0; s < 4; s++)
      KN[t][s] = *reinterpret_cast<const bf16x8*>(
          Kh + (size_t)(KNB + t * 32 + lq) * 64 + s * 16 + h * 8);

  // tile max (tree, depth 4) then combine halves
  float red[16];
#pragma unroll
  for (int j = 0; j < 16; j++) red[j] = fmaxf(st[0][j], st[1][j]);
#pragma unroll
  for (int w = 8; w >= 1; w >>= 1)
#pragma unroll
    for (int j = 0; j < w; j++) red[j] = fmaxf(red[j], red[j + w]);
  float pmax = fmaxf(red[0], __shfl_xor(red[0], 32));

  // defer-max: rescale only when running max grew by > 8 (log2 domain)
  if (!__all(pmax - m <= 8.0f)) {
    float mnew = fmaxf(m, pmax);
    float alpha = exp2f(m - mnew);
    m = mnew;
    lsum *= alpha;
#pragma unroll
    for (int r = 0; r < 16; r++) {
      float ar = __shfl(alpha, (r & 3) + 8 * (r >> 2) + 4 * h);
      oacc[0][r] *= ar;
      oacc[1][r] *= ar;
    }
  }

  // P = exp2(S - m), partial row sums (ILP)
  float s0 = 0.f, s1 = 0.f, s2 = 0.f, s3 = 0.f;
#pragma unroll
  for (int t = 0; t < 2; t++)
#pragma unroll
    for (int j = 0; j < 16; j += 4) {
      float p0 = exp2f(st[t][j + 0] - m);
      float p1 = exp2f(st[t][j + 1] - m);
      float p2 = exp2f(st[t][j + 2] - m);
      float p3 = exp2f(st[t][j + 3] - m);
      st[t][j + 0] = p0; st[t][j + 1] = p1; st[t][j + 2] = p2; st[t][j + 3] = p3;
      s0 += p0; s1 += p1; s2 += p2; s3 += p3;
    }
  float rs = (s0 + s1) + (s2 + s3);
  rs += __shfl_xor(rs, 32);
  lsum += rs;

  // Build PV A-fragments in-register: for k-slice ks, lane needs
  // P[q=lq][k = ks*16 + h*8 + 0..7]; half of those live at lane^32.
  uint4 pa[4];
#pragma unroll
  for (int ks = 0; ks < 4; ks++) {
    const int t = ks >> 1, rlo = (ks & 1) * 8;
    u32 w0 = pk2(st[t][rlo + 0], st[t][rlo + 1]);
    u32 w1 = pk2(st[t][rlo + 2], st[t][rlo + 3]);
    u32 w2 = pk2(st[t][rlo + 4], st[t][rlo + 5]);
    u32 w3 = pk2(st[t][rlo + 6], st[t][rlo + 7]);
    u32 ka = h ? w2 : w0, kb2 = h ? w3 : w1;
    u32 sa = h ? w0 : w2, sb = h ? w1 : w3;
    u32 ra = (u32)__shfl_xor((int)sa, 32);
    u32 rb = (u32)__shfl_xor((int)sb, 32);
    pa[ks].x = h ? ra : ka;
    pa[ks].y = h ? rb : kb2;
    pa[ks].z = h ? ka : ra;
    pa[ks].w = h ? kb2 : rb;
  }

  // PV: O[q][d] += P * V
#pragma unroll
  for (int dt = 0; dt < 2; dt++)
#pragma unroll
    for (int ks = 0; ks < 4; ks++) {
      union { uint4 u; bf16x8 v; } pu;
      pu.u = pa[ks];
      oacc[dt] = mfma32(pu.v, vreg[dt][ks], oacc[dt]);
    }
}

__global__ __launch_bounds__(256, 2) void attn_kernel(const u16* __restrict__ Q,
                                                      const u16* __restrict__ Kt,
                                                      const u16* __restrict__ VT,
                                                      u16* __restrict__ O) {
  const int tid = threadIdx.x;
  const int wid = tid >> 6, l = tid & 63;
  const int lq = l & 31, h = l >> 5;
  const int b = blockIdx.z, hd = blockIdx.y;
  const int qbase = blockIdx.x * 128 + wid * 32;
  const size_t hoff = (size_t)(b * 8 + hd) * 2048 * 64;
  const u16* Qh = Q + hoff;
  const u16* Kh = Kt + hoff;
  const u16* Vh = VT + hoff;   // [D=64][N=2048]

  bf16x8 qf[4];
#pragma unroll
  for (int s = 0; s < 4; s++)
    qf[s] = *reinterpret_cast<const bf16x8*>(Qh + (size_t)(qbase + lq) * 64 + s * 16 + h * 8);

  f32x16 oacc[2];
#pragma unroll
  for (int r = 0; r < 16; r++) { oacc[0][r] = 0.f; oacc[1][r] = 0.f; }
  float m = -INFINITY, lsum = 0.f;

  // named K double-buffers, manual 2x body (no runtime-indexed frag arrays)
  bf16x8 kA[2][4], kB[2][4];
#pragma unroll
  for (int t = 0; t < 2; t++)
#pragma unroll
    for (int s = 0; s < 4; s++)
      kA[t][s] = *reinterpret_cast<const bf16x8*>(
          Kh + (size_t)(t * 32 + lq) * 64 + s * 16 + h * 8);

  for (int kb = 0; kb < 2048; kb += 128) {
    attn_tile(kb,       kb + 64,            Kh, Vh, qf, kA, kB, oacc, m, lsum, lq, h);
    attn_tile(kb + 64, (kb + 128) & 2047,   Kh, Vh, qf, kB, kA, oacc, m, lsum, lq, h);
  }

  float linv = 1.0f / lsum;
#pragma unroll
  for (int r = 0; r < 16; r++) {
    const int qr = (r & 3) + 8 * (r >> 2) + 4 * h;
    float lb = __shfl(linv, qr);
    int row = qbase + qr;
#pragma unroll
    for (int dt = 0; dt < 2; dt++) {
      int col = hd * 64 + dt * 32 + lq;
      O[((size_t)(b * 2048) + row) * 512 + col] = f2bf(oacc[dt][r] * lb);
    }
  }
}

extern "C" void kernel_launch(void* const* d_in, const int* in_sizes, int n_in,
                              void* d_out, int out_size, void* d_ws, size_t ws_size,
                              hipStream_t stream) {
  const float* x      = (const float*)d_in[0];
  const float* ln1_g  = (const float*)d_in[1];
  const float* ln1_b  = (const float*)d_in[2];
  const float* w_qkv  = (const float*)d_in[3];
  const float* b_qkv  = (const float*)d_in[4];
  const float* w_proj = (const float*)d_in[5];
  const float* b_proj = (const float*)d_in[6];
  const float* ln2_g  = (const float*)d_in[7];
  const float* ln2_b  = (const float*)d_in[8];
  const float* w1     = (const float*)d_in[9];
  const float* b1     = (const float*)d_in[10];
  const float* w2     = (const float*)d_in[11];
  const float* b2     = (const float*)d_in[12];
  float* out = (float*)d_out;

  const int M = 8192;  // B*N rows
  char* w = (char*)d_ws;
  u16* wqkvT  = (u16*)w; w += (size_t)1536 * 512 * 2;
  u16* wprojT = (u16*)w; w += (size_t)512 * 512 * 2;
  u16* w1T    = (u16*)w; w += (size_t)2048 * 512 * 2;
  u16* w2T    = (u16*)w; w += (size_t)512 * 2048 * 2;
  u16* h1     = (u16*)w; w += (size_t)M * 512 * 2;
  u16* Qb     = (u16*)w; w += (size_t)M * 512 * 2;
  u16* Kb     = (u16*)w; w += (size_t)M * 512 * 2;
  u16* VTb    = (u16*)w; w += (size_t)M * 512 * 2;
  u16* attn   = (u16*)w; w += (size_t)M * 512 * 2;
  u16* h2     = (u16*)w; w += (size_t)M * 512 * 2;
  u16* mid    = (u16*)w; w += (size_t)M * 2048 * 2;

  cast_transpose<<<(512 * 1536 + 255) / 256, 256, 0, stream>>>(w_qkv, wqkvT, 512, 1536);
  cast_transpose<<<(512 * 512 + 255) / 256, 256, 0, stream>>>(w_proj, wprojT, 512, 512);
  cast_transpose<<<(512 * 2048 + 255) / 256, 256, 0, stream>>>(w1, w1T, 512, 2048);
  cast_transpose<<<(2048 * 512 + 255) / 256, 256, 0, stream>>>(w2, w2T, 2048, 512);

  ln_kernel<<<M, 64, 0, stream>>>(x, ln1_g, ln1_b, h1);

  gemm_bt<0, 128><<<dim3(1536 / 128, M / 128), 256, 0, stream>>>(
      h1, wqkvT, M, 1536, 512, b_qkv, nullptr, nullptr, nullptr, Qb, Kb, VTb);

  attn_kernel<<<dim3(2048 / 128, 8, 4), 256, 0, stream>>>(Qb, Kb, VTb, attn);

  gemm_bt<1, 64><<<dim3(512 / 128, M / 64), 256, 0, stream>>>(
      attn, wprojT, M, 512, 512, b_proj, x, out, nullptr, nullptr, nullptr, nullptr);

  ln_kernel<<<M, 64, 0, stream>>>(out, ln2_g, ln2_b, h2);

  gemm_bt<2, 128><<<dim3(2048 / 128, M / 128), 256, 0, stream>>>(
      h2, w1T, M, 2048, 512, b1, nullptr, nullptr, mid, nullptr, nullptr, nullptr);

  gemm_bt<3, 64><<<dim3(512 / 128, M / 64), 256, 0, stream>>>(
      mid, w2T, M, 512, 2048, b2, out, out, nullptr, nullptr, nullptr, nullptr);
}